// Round 6
// baseline (245.915 us; speedup 1.0000x reference)
//
#include <hip/hip_runtime.h>
#include <hip/hip_bf16.h>

// RAVNet ragged attention, bf16 MFMA version, v7 (de-scratch + fused q-tiles).
// B=4096 groups, C=81, DK=64, N<=128. One 256-thread block (4 waves) per group.
// v7 changes vs v6 (135us kernel, regression):
//  - v6's loadx(f32x4* out) array-out-param defeated SROA -> one f32x4/thread
//    in scratch -> +16.5MB HBM writes (= the 15us regression). Now x loads go
//    through by-value ld4u() into NAMED f32x4 locals: no scratch.
//  - Phase 2 fuses both q-tiles (t=0,1) in one pass (compile-time DUAL path,
//    wave-uniform branch): K/V LDS fragments and wuT fragments are identical
//    across t, so loads are shared (halved) and the two MFMA chains are
//    independent -> scheduler interleaves them (latency hiding within wave).
//  - Keeps: LPT-sorted dispatch, no-max softmax, HW bf16 cvt, weight-fragment
//    reuse in phase 1, XOR-swizzled 32KB LDS, quad-shuffle transposes,
//    vectorized 16B epilogue stores.

typedef __attribute__((ext_vector_type(8))) short short8;   // 8 bf16 = 4 VGPRs
typedef __attribute__((ext_vector_type(4))) float f32x4;
typedef __attribute__((ext_vector_type(4))) short short4v;

constexpr int C  = 81;
constexpr int DK = 64;
constexpr int CP = 96;     // C padded to 3*32 for K-dim of projections

// ---- LDS layout (ushort units), XOR-swizzled, zero padding ----
constexpr int OFF_K  = 0;          // K: 128 rows x 64 ushorts (128 B/row)
constexpr int OFF_VT = 128 * 64;   // VT: 64 dims x 128 ushorts (256 B/row)
constexpr int SMEM_TOT = OFF_VT + 64 * 128;   // 16384 ushorts = 32,768 B

__device__ inline int kidx(int row, int colu) {   // colu in [0,64), mult of 4
    return OFF_K + row * 64 + (colu ^ ((row & 7) << 3));
}
__device__ inline int vidx(int dim, int colu) {   // colu in [0,128), mult of 4
    return OFF_VT + dim * 128 + (colu ^ ((dim & 15) << 3));
}

__device__ inline ushort f2b(float f) {   // fp32 -> bf16 bits, RNE (HW cvt)
    __hip_bfloat16 h = __float2bfloat16(f);
    return *reinterpret_cast<ushort*>(&h);
}
__device__ inline uint pack2bf(float a, float b) {
    return (uint)f2b(a) | ((uint)f2b(b) << 16);
}
__device__ inline uint shflu(uint v, int srcLane) {
    return (uint)__shfl((int)v, srcLane, 64);
}
union U8 { short8 s; uint u[4]; };

__device__ __forceinline__ f32x4 ld4u(const float* p) {   // unaligned 16B load
    f32x4 v;
    __builtin_memcpy(&v, p, 16);
    return v;
}

__device__ inline short8 cvt8(const f32x4 u0, const f32x4 u1) {
    short8 a;
    #pragma unroll
    for (int e = 0; e < 4; e++) {
        a[e]     = (short)f2b(u0[e]);
        a[e + 4] = (short)f2b(u1[e]);
    }
    return a;
}

#define MFMA16(a, b, c) __builtin_amdgcn_mfma_f32_16x16x32_bf16((a), (b), (c), 0, 0, 0)

// C-layout pair (2 uints = 4 bf16 rows) -> fragment dwords via quad shuffle
#define XPOSE(dst, pA0, pA1, pB0, pB1) do {                                   \
    uint _a0 = shflu(pA0, srcE), _b0 = shflu(pB0, srcE);                      \
    uint _a1 = shflu(pA1, srcE), _b1 = shflu(pB1, srcE);                      \
    uint _a2 = shflu(pA0, srcO), _b2 = shflu(pB0, srcO);                      \
    uint _a3 = shflu(pA1, srcO), _b3 = shflu(pB1, srcO);                      \
    U8 _u;                                                                    \
    _u.u[0] = hi ? _b0 : _a0;  _u.u[1] = hi ? _b1 : _a1;                      \
    _u.u[2] = hi ? _b2 : _a2;  _u.u[3] = hi ? _b3 : _a3;                      \
    dst = _u.s; } while (0)

struct BT { static constexpr bool value = true;  };
struct BF { static constexpr bool value = false; };

// ------- Kernel 1: scan + LPT counting sort -> meta[pos] = offset | (N<<24) -------
__global__ void scan_counts(const int* __restrict__ counts,
                            uint* __restrict__ meta, int n) {
    __shared__ int part[256];
    __shared__ int hist[129];
    __shared__ int start[130];
    const int tid = threadIdx.x;
    for (int i = tid; i < 129; i += 256) hist[i] = 0;
    __syncthreads();
    const int per = (n + 255) >> 8;
    const int base = tid * per;
    int s = 0;
    for (int i = 0; i < per; i++) {
        const int idx = base + i;
        if (idx < n) {
            int c = counts[idx];
            if (c < 0) c = 0; if (c > 128) c = 128;
            s += counts[idx];
            atomicAdd(&hist[c], 1);
        }
    }
    part[tid] = s;
    __syncthreads();
    for (int off = 1; off < 256; off <<= 1) {
        const int v = (tid >= off) ? part[tid - off] : 0;
        __syncthreads();
        part[tid] += v;
        __syncthreads();
    }
    if (tid == 0) {   // descending-N bin starts: big groups dispatch first
        start[128] = 0;
        for (int c = 127; c >= 0; c--) start[c] = start[c + 1] + hist[c + 1];
    }
    __syncthreads();
    int run = (tid == 0) ? 0 : part[tid - 1];
    for (int i = 0; i < per; i++) {
        const int idx = base + i;
        if (idx < n) {
            int c = counts[idx];
            int cc = c; if (cc < 0) cc = 0; if (cc > 128) cc = 128;
            const int pos = atomicAdd(&start[cc], 1);
            meta[pos] = (uint)run | ((uint)c << 24);
            run += c;
        }
    }
}

// ------- Kernel 2: weights -> bf16, transposed for contiguous fragments -------
// wqT/wkT/wvT: [64][96]  wT[n][k] = W[k][n] (k<81, else 0); wvT folds prior@wv.
// wuT: [96][64] wuT[n][k] = wu[k][n] (n<81, else 0).
__global__ void prep_weights(const float* __restrict__ prior,
                             const float* __restrict__ wq, const float* __restrict__ wk,
                             const float* __restrict__ wv, const float* __restrict__ wu,
                             ushort* __restrict__ wqT, ushort* __restrict__ wkT,
                             ushort* __restrict__ wvT, ushort* __restrict__ wuT) {
    int idx = blockIdx.x * 256 + threadIdx.x;
    int sec = idx / (DK * CP);
    int i   = idx - sec * (DK * CP);
    if (sec == 0 || sec == 1) {
        int n = i / CP, k = i - (i / CP) * CP;
        const float* w = (sec == 0) ? wq : wk;
        ushort* dst    = (sec == 0) ? wqT : wkT;
        dst[n * CP + k] = (k < C) ? f2b(w[k * DK + n]) : (ushort)0;
    } else if (sec == 2) {
        int n = i / CP, k = i - (i / CP) * CP;
        float s = 0.f;
        if (k < C)
            for (int e = 0; e < C; e++) s = fmaf(prior[k * C + e], wv[e * DK + n], s);
        wvT[n * CP + k] = (k < C) ? f2b(s) : (ushort)0;
    } else {
        int n = i / DK, k = i - (i / DK) * DK;   // n < 96, k < 64
        wuT[n * DK + k] = (n < C) ? f2b(wu[k * C + n]) : (ushort)0;
    }
}

// ---------------- Kernel 3: per-group MFMA attention ----------------
__launch_bounds__(256, 4)
__global__ void ravnet_mfma(const float* __restrict__ x,
                            const uint* __restrict__ meta,
                            const ushort* __restrict__ wqT, const ushort* __restrict__ wkT,
                            const ushort* __restrict__ wvT, const ushort* __restrict__ wuT,
                            const float* __restrict__ bq, const float* __restrict__ bk,
                            const float* __restrict__ bv, const float* __restrict__ bu,
                            float* __restrict__ out) {
    __shared__ __align__(16) ushort sm[SMEM_TOT];   // 32,768 B

    const uint mw  = meta[blockIdx.x];
    const int  N   = (int)(mw >> 24);
    const long off = (long)(mw & 0xFFFFFFu);
    const int tid  = threadIdx.x;
    const int lane = tid & 63;
    const int wave = tid >> 6;
    const int quad = lane >> 4;      // 0..3
    const int m16  = lane & 15;      // 0..15
    const int NT8  = (N + 15) >> 4;  // 16-row tiles, <=8
    const int NT4  = (N + 31) >> 5;  // 32-col K-steps for P@V, <=4
    const float* xsrc = x + off * C;

    // quad-shuffle constants: C-layout (lane holds M[m16][tile*16+quad*4+r])
    // -> fragment layout (lane holds M[m16][kstep*32+quad*8+e]).
    const int srcE = ((quad & 1) << 5) + m16;
    const int srcO = srcE + 16;
    const bool hi  = (quad >> 1) != 0;

    // Q fragments for this wave's q-tiles {wave, wave+4}
    short8 aq[2][2];

    // ---- Phase 1 (row-split): wave w computes Q/K/V for row tiles {w, w+4}. ----
    const bool a0 = wave < NT8;
    const bool a1 = (wave + 4) < NT8;
    if (a0) {
        // (1) all raw x chunks into NAMED registers (SROA-safe, one drain).
        const int c0 = quad * 8;
        const int row0 = wave * 16 + m16;
        const int row1 = (wave + 4) * 16 + m16;
        const float* xr0 = xsrc + (long)((row0 < N) ? row0 : (N - 1)) * C;
        const float* xr1 = a1 ? (xsrc + (long)((row1 < N) ? row1 : (N - 1)) * C) : xr0;
        f32x4 p00 = ld4u(xr0 + c0),      p01 = ld4u(xr0 + c0 + 4);
        f32x4 p02 = ld4u(xr0 + 32 + c0), p03 = ld4u(xr0 + 32 + c0 + 4);
        f32x4 p10 = ld4u(xr1 + c0),      p11 = ld4u(xr1 + c0 + 4);
        f32x4 p12 = ld4u(xr1 + 32 + c0), p13 = ld4u(xr1 + 32 + c0 + 4);
        f32x4 p04 = {0.f, 0.f, 0.f, 0.f}, p05 = {0.f, 0.f, 0.f, 0.f};
        f32x4 p14 = {0.f, 0.f, 0.f, 0.f}, p15 = {0.f, 0.f, 0.f, 0.f};
        if (quad < 2) {              // cols 64..79 fully valid
            p04 = ld4u(xr0 + 64 + c0); p05 = ld4u(xr0 + 64 + c0 + 4);
            p14 = ld4u(xr1 + 64 + c0); p15 = ld4u(xr1 + 64 + c0 + 4);
        } else if (quad == 2) {      // col 80 only (81..87 hit zero wT rows)
            p04[0] = xr0[80];
            p14[0] = xr1[80];
        }                            // quad 3: cols 88..95 -> zero
        // (2) convert to bf16 A-fragments (v_cvt_pk_bf16_f32 pairs)
        short8 ax2[2][3];
        ax2[0][0] = cvt8(p00, p01);
        ax2[0][1] = cvt8(p02, p03);
        ax2[0][2] = cvt8(p04, p05);
        if (a1) {
            ax2[1][0] = cvt8(p10, p11);
            ax2[1][1] = cvt8(p12, p13);
            ax2[1][2] = cvt8(p14, p15);
        }
        // (3) Q^T: frags loaded once, both tiles; pack; quad-shuffle -> aq
        uint qpk[2][4][2];
        #pragma unroll
        for (int nt = 0; nt < 4; nt++) {
            const ushort* wp = wqT + (nt * 16 + m16) * CP + quad * 8;
            const short8 f0 = *(const short8*)(wp);
            const short8 f1 = *(const short8*)(wp + 32);
            const short8 f2 = *(const short8*)(wp + 64);
            const f32x4 b4 = *(const f32x4*)(bq + nt * 16 + quad * 4);
            {
                f32x4 acc = {0.f, 0.f, 0.f, 0.f};
                acc = MFMA16(f0, ax2[0][0], acc);
                acc = MFMA16(f1, ax2[0][1], acc);
                acc = MFMA16(f2, ax2[0][2], acc);
                qpk[0][nt][0] = pack2bf(acc[0] + b4[0], acc[1] + b4[1]);
                qpk[0][nt][1] = pack2bf(acc[2] + b4[2], acc[3] + b4[3]);
            }
            if (a1) {
                f32x4 acc = {0.f, 0.f, 0.f, 0.f};
                acc = MFMA16(f0, ax2[1][0], acc);
                acc = MFMA16(f1, ax2[1][1], acc);
                acc = MFMA16(f2, ax2[1][2], acc);
                qpk[1][nt][0] = pack2bf(acc[0] + b4[0], acc[1] + b4[1]);
                qpk[1][nt][1] = pack2bf(acc[2] + b4[2], acc[3] + b4[3]);
            }
        }
        #pragma unroll
        for (int ks = 0; ks < 2; ks++)
            XPOSE(aq[0][ks], qpk[0][2 * ks][0], qpk[0][2 * ks][1],
                             qpk[0][2 * ks + 1][0], qpk[0][2 * ks + 1][1]);
        if (a1) {
            #pragma unroll
            for (int ks = 0; ks < 2; ks++)
                XPOSE(aq[1][ks], qpk[1][2 * ks][0], qpk[1][2 * ks][1],
                                 qpk[1][2 * ks + 1][0], qpk[1][2 * ks + 1][1]);
        }
        // (4) K^T: frags once, both tiles -> 8B swizzled stores
        #pragma unroll
        for (int nt = 0; nt < 4; nt++) {
            const ushort* wp = wkT + (nt * 16 + m16) * CP + quad * 8;
            const short8 f0 = *(const short8*)(wp);
            const short8 f1 = *(const short8*)(wp + 32);
            const short8 f2 = *(const short8*)(wp + 64);
            const f32x4 b4 = *(const f32x4*)(bk + nt * 16 + quad * 4);
            {
                f32x4 acc = {0.f, 0.f, 0.f, 0.f};
                acc = MFMA16(f0, ax2[0][0], acc);
                acc = MFMA16(f1, ax2[0][1], acc);
                acc = MFMA16(f2, ax2[0][2], acc);
                short4v pk4;
                #pragma unroll
                for (int r = 0; r < 4; r++) pk4[r] = (short)f2b(acc[r] + b4[r]);
                *(short4v*)(sm + kidx(wave * 16 + m16, nt * 16 + quad * 4)) = pk4;
            }
            if (a1) {
                f32x4 acc = {0.f, 0.f, 0.f, 0.f};
                acc = MFMA16(f0, ax2[1][0], acc);
                acc = MFMA16(f1, ax2[1][1], acc);
                acc = MFMA16(f2, ax2[1][2], acc);
                short4v pk4;
                #pragma unroll
                for (int r = 0; r < 4; r++) pk4[r] = (short)f2b(acc[r] + b4[r]);
                *(short4v*)(sm + kidx((wave + 4) * 16 + m16, nt * 16 + quad * 4)) = pk4;
            }
        }
        // (5) V: frags once, both tiles -> VT 8B swizzled stores
        #pragma unroll
        for (int nt = 0; nt < 4; nt++) {
            const ushort* wp = wvT + (nt * 16 + m16) * CP + quad * 8;
            const short8 f0 = *(const short8*)(wp);
            const short8 f1 = *(const short8*)(wp + 32);
            const short8 f2 = *(const short8*)(wp + 64);
            const float bb = bv[nt * 16 + m16];
            {
                f32x4 acc = {0.f, 0.f, 0.f, 0.f};
                acc = MFMA16(ax2[0][0], f0, acc);
                acc = MFMA16(ax2[0][1], f1, acc);
                acc = MFMA16(ax2[0][2], f2, acc);
                short4v pk4;
                #pragma unroll
                for (int r = 0; r < 4; r++) pk4[r] = (short)f2b(acc[r] + bb);
                *(short4v*)(sm + vidx(nt * 16 + m16, wave * 16 + quad * 4)) = pk4;
            }
            if (a1) {
                f32x4 acc = {0.f, 0.f, 0.f, 0.f};
                acc = MFMA16(ax2[1][0], f0, acc);
                acc = MFMA16(ax2[1][1], f1, acc);
                acc = MFMA16(ax2[1][2], f2, acc);
                short4v pk4;
                #pragma unroll
                for (int r = 0; r < 4; r++) pk4[r] = (short)f2b(acc[r] + bb);
                *(short4v*)(sm + vidx(nt * 16 + m16, (wave + 4) * 16 + quad * 4)) = pk4;
            }
        }
    }
    // VT pad cols [NT8*16, NT4*32) must be finite (P=0 there; NaN*0=NaN). Only
    // exists when NT8 is odd: zero 16 cols x 64 dims (1 store/thread).
    if (NT8 & 1) {
        const int R = NT8 * 16;
        const int d = tid >> 2, c4 = (tid & 3) << 2;
        short4v z = {0, 0, 0, 0};
        *(short4v*)(sm + vidx(d, R + c4)) = z;
    }
    __syncthreads();

    // ---- Phase 2: both q-tiles fused; K/V/Wu fragments shared across tiles ----
    constexpr float SCALE = 0.18033688011112042f;   // 0.125 * log2(e)
    auto phase2 = [&](auto dualc) {
        constexpr bool DUAL = decltype(dualc)::value;
        // (a) S^T = K Q^T for both tiles off shared kb
        f32x4 s0[8], s1[8];
        #pragma unroll
        for (int ct = 0; ct < 8; ct++) if (ct < NT8) {
            f32x4 A0 = {0.f, 0.f, 0.f, 0.f};
            f32x4 A1 = {0.f, 0.f, 0.f, 0.f};
            #pragma unroll
            for (int ks = 0; ks < 2; ks++) {
                short8 kb = *(const short8*)(sm + kidx(ct * 16 + m16, ks * 32 + quad * 8));
                A0 = MFMA16(kb, aq[0][ks], A0);
                if (DUAL) A1 = MFMA16(kb, aq[1][ks], A1);
            }
            s0[ct] = A0;
            if (DUAL) s1[ct] = A1;
        }
        // (b) softmax over keys, no max-pass (exp2 arg bounded ~ +-10)
        float lr0 = 0.f, lr1 = 0.f;
        #pragma unroll
        for (int ct = 0; ct < 8; ct++) if (ct < NT8) {
            #pragma unroll
            for (int r = 0; r < 4; r++) {
                const bool valid = (ct * 16 + quad * 4 + r) < N;
                float p0 = valid ? __builtin_exp2f(s0[ct][r] * SCALE) : 0.f;
                s0[ct][r] = p0; lr0 += p0;
                if (DUAL) {
                    float p1 = valid ? __builtin_exp2f(s1[ct][r] * SCALE) : 0.f;
                    s1[ct][r] = p1; lr1 += p1;
                }
            }
        }
        lr0 += __shfl_xor(lr0, 16, 64);
        lr0 += __shfl_xor(lr0, 32, 64);
        const float linv0 = 1.f / lr0;
        float linv1 = 0.f;
        if (DUAL) {
            lr1 += __shfl_xor(lr1, 16, 64);
            lr1 += __shfl_xor(lr1, 32, 64);
            linv1 = 1.f / lr1;
        }
        // (c) P pack + quad-shuffle -> PV B-fragments (pad tiles = 0)
        uint pk0[8][2], pk1[8][2];
        #pragma unroll
        for (int ct = 0; ct < 8; ct++) {
            if (ct < NT8) {
                pk0[ct][0] = pack2bf(s0[ct][0], s0[ct][1]);
                pk0[ct][1] = pack2bf(s0[ct][2], s0[ct][3]);
                if (DUAL) {
                    pk1[ct][0] = pack2bf(s1[ct][0], s1[ct][1]);
                    pk1[ct][1] = pack2bf(s1[ct][2], s1[ct][3]);
                }
            } else {
                pk0[ct][0] = 0u; pk0[ct][1] = 0u;
                if (DUAL) { pk1[ct][0] = 0u; pk1[ct][1] = 0u; }
            }
        }
        short8 ap0[4], ap1[4];
        #pragma unroll
        for (int kt = 0; kt < 4; kt++) if (kt < NT4) {
            XPOSE(ap0[kt], pk0[2 * kt][0], pk0[2 * kt][1],
                           pk0[2 * kt + 1][0], pk0[2 * kt + 1][1]);
            if (DUAL)
                XPOSE(ap1[kt], pk1[2 * kt][0], pk1[2 * kt][1],
                               pk1[2 * kt + 1][0], pk1[2 * kt + 1][1]);
        }
        // (d) O^T = V^T P^T off shared vb
        uint opk0[4][2], opk1[4][2];
        #pragma unroll
        for (int ot = 0; ot < 4; ot++) {
            f32x4 o0 = {0.f, 0.f, 0.f, 0.f};
            f32x4 o1 = {0.f, 0.f, 0.f, 0.f};
            #pragma unroll
            for (int kt = 0; kt < 4; kt++) if (kt < NT4) {
                short8 vb = *(const short8*)(sm + vidx(ot * 16 + m16, kt * 32 + quad * 8));
                o0 = MFMA16(vb, ap0[kt], o0);
                if (DUAL) o1 = MFMA16(vb, ap1[kt], o1);
            }
            opk0[ot][0] = pack2bf(o0[0] * linv0, o0[1] * linv0);
            opk0[ot][1] = pack2bf(o0[2] * linv0, o0[3] * linv0);
            if (DUAL) {
                opk1[ot][0] = pack2bf(o1[0] * linv1, o1[1] * linv1);
                opk1[ot][1] = pack2bf(o1[2] * linv1, o1[3] * linv1);
            }
        }
        // (e) quad-shuffle O^T -> out-proj B-fragments
        short8 ao0[2], ao1[2];
        #pragma unroll
        for (int ks = 0; ks < 2; ks++) {
            XPOSE(ao0[ks], opk0[2 * ks][0], opk0[2 * ks][1],
                           opk0[2 * ks + 1][0], opk0[2 * ks + 1][1]);
            if (DUAL)
                XPOSE(ao1[ks], opk1[2 * ks][0], opk1[2 * ks][1],
                               opk1[2 * ks + 1][0], opk1[2 * ks + 1][1]);
        }
        // (f) out^T = WuT O^T off shared wb; 16B stores (+1 scalar at e=80)
        const int xrow0 = wave * 16 + m16;
        const int xrow1 = (wave + 4) * 16 + m16;
        float* orow0 = out + (off + xrow0) * C;
        float* orow1 = out + (off + xrow1) * C;
        #pragma unroll
        for (int ct = 0; ct < 6; ct++) {
            const ushort* wp = wuT + (ct * 16 + m16) * DK + quad * 8;
            const short8 wb0 = *(const short8*)(wp);
            const short8 wb1 = *(const short8*)(wp + 32);
            f32x4 A0 = {0.f, 0.f, 0.f, 0.f};
            f32x4 A1 = {0.f, 0.f, 0.f, 0.f};
            A0 = MFMA16(wb0, ao0[0], A0);
            A0 = MFMA16(wb1, ao0[1], A0);
            if (DUAL) {
                A1 = MFMA16(wb0, ao1[0], A1);
                A1 = MFMA16(wb1, ao1[1], A1);
            }
            const int e0 = ct * 16 + quad * 4;
            if (e0 + 3 < C) {
                const f32x4 b4 = *(const f32x4*)(bu + e0);
                A0[0] += b4[0]; A0[1] += b4[1]; A0[2] += b4[2]; A0[3] += b4[3];
                if (xrow0 < N) __builtin_memcpy(orow0 + e0, &A0, 16);
                if (DUAL) {
                    A1[0] += b4[0]; A1[1] += b4[1]; A1[2] += b4[2]; A1[3] += b4[3];
                    if (xrow1 < N) __builtin_memcpy(orow1 + e0, &A1, 16);
                }
            } else if (e0 == 80) {
                if (xrow0 < N) orow0[80] = A0[0] + bu[80];
                if (DUAL && xrow1 < N) orow1[80] = A1[0] + bu[80];
            }
        }
    };
    if (a0) {
        if (a1) phase2(BT{});
        else    phase2(BF{});
    }
}

// ---------------- launch ----------------
extern "C" void kernel_launch(void* const* d_in, const int* in_sizes, int n_in,
                              void* d_out, int out_size, void* d_ws, size_t ws_size,
                              hipStream_t stream) {
    const float* x      = (const float*)d_in[0];
    const int*   counts = (const int*)  d_in[1];
    const float* prior  = (const float*)d_in[2];
    const float* wq     = (const float*)d_in[3];
    const float* bq     = (const float*)d_in[4];
    const float* wk     = (const float*)d_in[5];
    const float* bk     = (const float*)d_in[6];
    const float* wv     = (const float*)d_in[7];
    const float* bv     = (const float*)d_in[8];
    const float* wu     = (const float*)d_in[9];
    const float* bu     = (const float*)d_in[10];
    float* out = (float*)d_out;

    const int B = in_sizes[1];   // 4096 groups

    // ws: meta[B] (offset | N<<24, LPT-sorted) | wqT | wkT | wvT | wuT
    uint*   meta = (uint*)d_ws;
    ushort* wqT = (ushort*)((char*)d_ws + (((size_t)B * sizeof(uint) + 255) & ~(size_t)255));
    ushort* wkT = wqT + DK * CP;
    ushort* wvT = wkT + DK * CP;
    ushort* wuT = wvT + DK * CP;

    scan_counts<<<1, 256, 0, stream>>>(counts, meta, B);
    prep_weights<<<(4 * DK * CP + 255) / 256, 256, 0, stream>>>(
        prior, wq, wk, wv, wu, wqT, wkT, wvT, wuT);
    ravnet_mfma<<<B, 256, 0, stream>>>(x, meta,
                                       wqT, wkT, wvT, wuT,
                                       bq, bk, bv, bu, out);
}

// Round 7
// 240.427 us; speedup vs baseline: 1.0228x; 1.0228x over previous
//
#include <hip/hip_runtime.h>
#include <hip/hip_bf16.h>

// RAVNet ragged attention, bf16 MFMA version, v8 (spill elimination).
// B=4096 groups, C=81, DK=64, N<=128. One 256-thread block (4 waves) per group.
// v8 changes vs v7 (111us kernel):
//  - __launch_bounds__(256,3): v7's (256,4) capped VGPR at 128 while the DUAL
//    phase-2 peak live set is ~100-120 -> allocator spilled a few dwords/thread
//    (~25MB extra HBM WRITE_SIZE + scratch-read latency on the critical path).
//    Cap 170 gives slack; realized occupancy was already ~12 waves/CU.
//  - scan_counts + prep_weights merged into one prep_all launch (block 0 scans,
//    blocks 1..96 transpose weights): one fewer serial launch.
//  - Keeps: DUAL fused q-tiles, LPT-sorted dispatch, no-max softmax, HW bf16
//    cvt, named-register x loads, XOR-swizzled 32KB LDS, quad-shuffle
//    transposes, 16B epilogue stores.

typedef __attribute__((ext_vector_type(8))) short short8;   // 8 bf16 = 4 VGPRs
typedef __attribute__((ext_vector_type(4))) float f32x4;
typedef __attribute__((ext_vector_type(4))) short short4v;

constexpr int C  = 81;
constexpr int DK = 64;
constexpr int CP = 96;     // C padded to 3*32 for K-dim of projections

// ---- LDS layout (ushort units), XOR-swizzled, zero padding ----
constexpr int OFF_K  = 0;          // K: 128 rows x 64 ushorts (128 B/row)
constexpr int OFF_VT = 128 * 64;   // VT: 64 dims x 128 ushorts (256 B/row)
constexpr int SMEM_TOT = OFF_VT + 64 * 128;   // 16384 ushorts = 32,768 B

__device__ inline int kidx(int row, int colu) {   // colu in [0,64), mult of 4
    return OFF_K + row * 64 + (colu ^ ((row & 7) << 3));
}
__device__ inline int vidx(int dim, int colu) {   // colu in [0,128), mult of 4
    return OFF_VT + dim * 128 + (colu ^ ((dim & 15) << 3));
}

__device__ inline ushort f2b(float f) {   // fp32 -> bf16 bits, RNE (HW cvt)
    __hip_bfloat16 h = __float2bfloat16(f);
    return *reinterpret_cast<ushort*>(&h);
}
__device__ inline uint pack2bf(float a, float b) {
    return (uint)f2b(a) | ((uint)f2b(b) << 16);
}
__device__ inline uint shflu(uint v, int srcLane) {
    return (uint)__shfl((int)v, srcLane, 64);
}
union U8 { short8 s; uint u[4]; };

__device__ __forceinline__ f32x4 ld4u(const float* p) {   // unaligned 16B load
    f32x4 v;
    __builtin_memcpy(&v, p, 16);
    return v;
}

__device__ inline short8 cvt8(const f32x4 u0, const f32x4 u1) {
    short8 a;
    #pragma unroll
    for (int e = 0; e < 4; e++) {
        a[e]     = (short)f2b(u0[e]);
        a[e + 4] = (short)f2b(u1[e]);
    }
    return a;
}

#define MFMA16(a, b, c) __builtin_amdgcn_mfma_f32_16x16x32_bf16((a), (b), (c), 0, 0, 0)

// C-layout pair (2 uints = 4 bf16 rows) -> fragment dwords via quad shuffle
#define XPOSE(dst, pA0, pA1, pB0, pB1) do {                                   \
    uint _a0 = shflu(pA0, srcE), _b0 = shflu(pB0, srcE);                      \
    uint _a1 = shflu(pA1, srcE), _b1 = shflu(pB1, srcE);                      \
    uint _a2 = shflu(pA0, srcO), _b2 = shflu(pB0, srcO);                      \
    uint _a3 = shflu(pA1, srcO), _b3 = shflu(pB1, srcO);                      \
    U8 _u;                                                                    \
    _u.u[0] = hi ? _b0 : _a0;  _u.u[1] = hi ? _b1 : _a1;                      \
    _u.u[2] = hi ? _b2 : _a2;  _u.u[3] = hi ? _b3 : _a3;                      \
    dst = _u.s; } while (0)

struct BT { static constexpr bool value = true;  };
struct BF { static constexpr bool value = false; };

// ------- Kernel 1: prep_all. Block 0: scan + LPT counting sort ->
// meta[pos] = offset | (N<<24). Blocks 1..96: weights -> bf16 transposed.
// wqT/wkT/wvT: [64][96]  wT[n][k] = W[k][n] (k<81, else 0); wvT folds prior@wv.
// wuT: [96][64] wuT[n][k] = wu[k][n] (n<81, else 0).
__global__ void prep_all(const int* __restrict__ counts,
                         uint* __restrict__ meta, int n,
                         const float* __restrict__ prior,
                         const float* __restrict__ wq, const float* __restrict__ wk,
                         const float* __restrict__ wv, const float* __restrict__ wu,
                         ushort* __restrict__ wqT, ushort* __restrict__ wkT,
                         ushort* __restrict__ wvT, ushort* __restrict__ wuT) {
    const int tid = threadIdx.x;
    if (blockIdx.x == 0) {
        __shared__ int part[256];
        __shared__ int hist[129];
        __shared__ int start[130];
        for (int i = tid; i < 129; i += 256) hist[i] = 0;
        __syncthreads();
        const int per = (n + 255) >> 8;
        const int base = tid * per;
        int s = 0;
        for (int i = 0; i < per; i++) {
            const int idx = base + i;
            if (idx < n) {
                int c = counts[idx];
                if (c < 0) c = 0; if (c > 128) c = 128;
                s += counts[idx];
                atomicAdd(&hist[c], 1);
            }
        }
        part[tid] = s;
        __syncthreads();
        for (int off = 1; off < 256; off <<= 1) {
            const int v = (tid >= off) ? part[tid - off] : 0;
            __syncthreads();
            part[tid] += v;
            __syncthreads();
        }
        if (tid == 0) {   // descending-N bin starts: big groups dispatch first
            start[128] = 0;
            for (int c = 127; c >= 0; c--) start[c] = start[c + 1] + hist[c + 1];
        }
        __syncthreads();
        int run = (tid == 0) ? 0 : part[tid - 1];
        for (int i = 0; i < per; i++) {
            const int idx = base + i;
            if (idx < n) {
                int c = counts[idx];
                int cc = c; if (cc < 0) cc = 0; if (cc > 128) cc = 128;
                const int pos = atomicAdd(&start[cc], 1);
                meta[pos] = (uint)run | ((uint)c << 24);
                run += c;
            }
        }
    } else {
        int idx = (blockIdx.x - 1) * 256 + tid;
        int sec = idx / (DK * CP);
        int i   = idx - sec * (DK * CP);
        if (sec == 0 || sec == 1) {
            int nn = i / CP, k = i - (i / CP) * CP;
            const float* w = (sec == 0) ? wq : wk;
            ushort* dst    = (sec == 0) ? wqT : wkT;
            dst[nn * CP + k] = (k < C) ? f2b(w[k * DK + nn]) : (ushort)0;
        } else if (sec == 2) {
            int nn = i / CP, k = i - (i / CP) * CP;
            float s = 0.f;
            if (k < C)
                for (int e = 0; e < C; e++) s = fmaf(prior[k * C + e], wv[e * DK + nn], s);
            wvT[nn * CP + k] = (k < C) ? f2b(s) : (ushort)0;
        } else if (sec == 3) {
            int nn = i / DK, k = i - (i / DK) * DK;   // nn < 96, k < 64
            wuT[nn * DK + k] = (nn < C) ? f2b(wu[k * C + nn]) : (ushort)0;
        }
    }
}

// ---------------- Kernel 2: per-group MFMA attention ----------------
__launch_bounds__(256, 3)
__global__ void ravnet_mfma(const float* __restrict__ x,
                            const uint* __restrict__ meta,
                            const ushort* __restrict__ wqT, const ushort* __restrict__ wkT,
                            const ushort* __restrict__ wvT, const ushort* __restrict__ wuT,
                            const float* __restrict__ bq, const float* __restrict__ bk,
                            const float* __restrict__ bv, const float* __restrict__ bu,
                            float* __restrict__ out) {
    __shared__ __align__(16) ushort sm[SMEM_TOT];   // 32,768 B

    const uint mw  = meta[blockIdx.x];
    const int  N   = (int)(mw >> 24);
    const long off = (long)(mw & 0xFFFFFFu);
    const int tid  = threadIdx.x;
    const int lane = tid & 63;
    const int wave = tid >> 6;
    const int quad = lane >> 4;      // 0..3
    const int m16  = lane & 15;      // 0..15
    const int NT8  = (N + 15) >> 4;  // 16-row tiles, <=8
    const int NT4  = (N + 31) >> 5;  // 32-col K-steps for P@V, <=4
    const float* xsrc = x + off * C;

    // quad-shuffle constants: C-layout (lane holds M[m16][tile*16+quad*4+r])
    // -> fragment layout (lane holds M[m16][kstep*32+quad*8+e]).
    const int srcE = ((quad & 1) << 5) + m16;
    const int srcO = srcE + 16;
    const bool hi  = (quad >> 1) != 0;

    // Q fragments for this wave's q-tiles {wave, wave+4}
    short8 aq[2][2];

    // ---- Phase 1 (row-split): wave w computes Q/K/V for row tiles {w, w+4}. ----
    const bool a0 = wave < NT8;
    const bool a1 = (wave + 4) < NT8;
    if (a0) {
        // (1) all raw x chunks into NAMED registers (SROA-safe, one drain).
        const int c0 = quad * 8;
        const int row0 = wave * 16 + m16;
        const int row1 = (wave + 4) * 16 + m16;
        const float* xr0 = xsrc + (long)((row0 < N) ? row0 : (N - 1)) * C;
        const float* xr1 = a1 ? (xsrc + (long)((row1 < N) ? row1 : (N - 1)) * C) : xr0;
        f32x4 p00 = ld4u(xr0 + c0),      p01 = ld4u(xr0 + c0 + 4);
        f32x4 p02 = ld4u(xr0 + 32 + c0), p03 = ld4u(xr0 + 32 + c0 + 4);
        f32x4 p10 = ld4u(xr1 + c0),      p11 = ld4u(xr1 + c0 + 4);
        f32x4 p12 = ld4u(xr1 + 32 + c0), p13 = ld4u(xr1 + 32 + c0 + 4);
        f32x4 p04 = {0.f, 0.f, 0.f, 0.f}, p05 = {0.f, 0.f, 0.f, 0.f};
        f32x4 p14 = {0.f, 0.f, 0.f, 0.f}, p15 = {0.f, 0.f, 0.f, 0.f};
        if (quad < 2) {              // cols 64..79 fully valid
            p04 = ld4u(xr0 + 64 + c0); p05 = ld4u(xr0 + 64 + c0 + 4);
            p14 = ld4u(xr1 + 64 + c0); p15 = ld4u(xr1 + 64 + c0 + 4);
        } else if (quad == 2) {      // col 80 only (81..87 hit zero wT rows)
            p04[0] = xr0[80];
            p14[0] = xr1[80];
        }                            // quad 3: cols 88..95 -> zero
        // (2) convert to bf16 A-fragments (v_cvt_pk_bf16_f32 pairs)
        short8 ax2[2][3];
        ax2[0][0] = cvt8(p00, p01);
        ax2[0][1] = cvt8(p02, p03);
        ax2[0][2] = cvt8(p04, p05);
        if (a1) {
            ax2[1][0] = cvt8(p10, p11);
            ax2[1][1] = cvt8(p12, p13);
            ax2[1][2] = cvt8(p14, p15);
        }
        // (3) Q^T: frags loaded once, both tiles; pack; quad-shuffle -> aq
        uint qpk[2][4][2];
        #pragma unroll
        for (int nt = 0; nt < 4; nt++) {
            const ushort* wp = wqT + (nt * 16 + m16) * CP + quad * 8;
            const short8 f0 = *(const short8*)(wp);
            const short8 f1 = *(const short8*)(wp + 32);
            const short8 f2 = *(const short8*)(wp + 64);
            const f32x4 b4 = *(const f32x4*)(bq + nt * 16 + quad * 4);
            {
                f32x4 acc = {0.f, 0.f, 0.f, 0.f};
                acc = MFMA16(f0, ax2[0][0], acc);
                acc = MFMA16(f1, ax2[0][1], acc);
                acc = MFMA16(f2, ax2[0][2], acc);
                qpk[0][nt][0] = pack2bf(acc[0] + b4[0], acc[1] + b4[1]);
                qpk[0][nt][1] = pack2bf(acc[2] + b4[2], acc[3] + b4[3]);
            }
            if (a1) {
                f32x4 acc = {0.f, 0.f, 0.f, 0.f};
                acc = MFMA16(f0, ax2[1][0], acc);
                acc = MFMA16(f1, ax2[1][1], acc);
                acc = MFMA16(f2, ax2[1][2], acc);
                qpk[1][nt][0] = pack2bf(acc[0] + b4[0], acc[1] + b4[1]);
                qpk[1][nt][1] = pack2bf(acc[2] + b4[2], acc[3] + b4[3]);
            }
        }
        #pragma unroll
        for (int ks = 0; ks < 2; ks++)
            XPOSE(aq[0][ks], qpk[0][2 * ks][0], qpk[0][2 * ks][1],
                             qpk[0][2 * ks + 1][0], qpk[0][2 * ks + 1][1]);
        if (a1) {
            #pragma unroll
            for (int ks = 0; ks < 2; ks++)
                XPOSE(aq[1][ks], qpk[1][2 * ks][0], qpk[1][2 * ks][1],
                                 qpk[1][2 * ks + 1][0], qpk[1][2 * ks + 1][1]);
        }
        // (4) K^T: frags once, both tiles -> 8B swizzled stores
        #pragma unroll
        for (int nt = 0; nt < 4; nt++) {
            const ushort* wp = wkT + (nt * 16 + m16) * CP + quad * 8;
            const short8 f0 = *(const short8*)(wp);
            const short8 f1 = *(const short8*)(wp + 32);
            const short8 f2 = *(const short8*)(wp + 64);
            const f32x4 b4 = *(const f32x4*)(bk + nt * 16 + quad * 4);
            {
                f32x4 acc = {0.f, 0.f, 0.f, 0.f};
                acc = MFMA16(f0, ax2[0][0], acc);
                acc = MFMA16(f1, ax2[0][1], acc);
                acc = MFMA16(f2, ax2[0][2], acc);
                short4v pk4;
                #pragma unroll
                for (int r = 0; r < 4; r++) pk4[r] = (short)f2b(acc[r] + b4[r]);
                *(short4v*)(sm + kidx(wave * 16 + m16, nt * 16 + quad * 4)) = pk4;
            }
            if (a1) {
                f32x4 acc = {0.f, 0.f, 0.f, 0.f};
                acc = MFMA16(f0, ax2[1][0], acc);
                acc = MFMA16(f1, ax2[1][1], acc);
                acc = MFMA16(f2, ax2[1][2], acc);
                short4v pk4;
                #pragma unroll
                for (int r = 0; r < 4; r++) pk4[r] = (short)f2b(acc[r] + b4[r]);
                *(short4v*)(sm + kidx((wave + 4) * 16 + m16, nt * 16 + quad * 4)) = pk4;
            }
        }
        // (5) V: frags once, both tiles -> VT 8B swizzled stores
        #pragma unroll
        for (int nt = 0; nt < 4; nt++) {
            const ushort* wp = wvT + (nt * 16 + m16) * CP + quad * 8;
            const short8 f0 = *(const short8*)(wp);
            const short8 f1 = *(const short8*)(wp + 32);
            const short8 f2 = *(const short8*)(wp + 64);
            const float bb = bv[nt * 16 + m16];
            {
                f32x4 acc = {0.f, 0.f, 0.f, 0.f};
                acc = MFMA16(ax2[0][0], f0, acc);
                acc = MFMA16(ax2[0][1], f1, acc);
                acc = MFMA16(ax2[0][2], f2, acc);
                short4v pk4;
                #pragma unroll
                for (int r = 0; r < 4; r++) pk4[r] = (short)f2b(acc[r] + bb);
                *(short4v*)(sm + vidx(nt * 16 + m16, wave * 16 + quad * 4)) = pk4;
            }
            if (a1) {
                f32x4 acc = {0.f, 0.f, 0.f, 0.f};
                acc = MFMA16(ax2[1][0], f0, acc);
                acc = MFMA16(ax2[1][1], f1, acc);
                acc = MFMA16(ax2[1][2], f2, acc);
                short4v pk4;
                #pragma unroll
                for (int r = 0; r < 4; r++) pk4[r] = (short)f2b(acc[r] + bb);
                *(short4v*)(sm + vidx(nt * 16 + m16, (wave + 4) * 16 + quad * 4)) = pk4;
            }
        }
    }
    // VT pad cols [NT8*16, NT4*32) must be finite (P=0 there; NaN*0=NaN). Only
    // exists when NT8 is odd: zero 16 cols x 64 dims (1 store/thread).
    if (NT8 & 1) {
        const int R = NT8 * 16;
        const int d = tid >> 2, c4 = (tid & 3) << 2;
        short4v z = {0, 0, 0, 0};
        *(short4v*)(sm + vidx(d, R + c4)) = z;
    }
    __syncthreads();

    // ---- Phase 2: both q-tiles fused; K/V/Wu fragments shared across tiles ----
    constexpr float SCALE = 0.18033688011112042f;   // 0.125 * log2(e)
    auto phase2 = [&](auto dualc) {
        constexpr bool DUAL = decltype(dualc)::value;
        // (a) S^T = K Q^T for both tiles off shared kb
        f32x4 s0[8], s1[8];
        #pragma unroll
        for (int ct = 0; ct < 8; ct++) if (ct < NT8) {
            f32x4 A0 = {0.f, 0.f, 0.f, 0.f};
            f32x4 A1 = {0.f, 0.f, 0.f, 0.f};
            #pragma unroll
            for (int ks = 0; ks < 2; ks++) {
                short8 kb = *(const short8*)(sm + kidx(ct * 16 + m16, ks * 32 + quad * 8));
                A0 = MFMA16(kb, aq[0][ks], A0);
                if (DUAL) A1 = MFMA16(kb, aq[1][ks], A1);
            }
            s0[ct] = A0;
            if (DUAL) s1[ct] = A1;
        }
        // (b) softmax over keys, no max-pass (exp2 arg bounded ~ +-10)
        float lr0 = 0.f, lr1 = 0.f;
        #pragma unroll
        for (int ct = 0; ct < 8; ct++) if (ct < NT8) {
            #pragma unroll
            for (int r = 0; r < 4; r++) {
                const bool valid = (ct * 16 + quad * 4 + r) < N;
                float p0 = valid ? __builtin_exp2f(s0[ct][r] * SCALE) : 0.f;
                s0[ct][r] = p0; lr0 += p0;
                if (DUAL) {
                    float p1 = valid ? __builtin_exp2f(s1[ct][r] * SCALE) : 0.f;
                    s1[ct][r] = p1; lr1 += p1;
                }
            }
        }
        lr0 += __shfl_xor(lr0, 16, 64);
        lr0 += __shfl_xor(lr0, 32, 64);
        const float linv0 = 1.f / lr0;
        float linv1 = 0.f;
        if (DUAL) {
            lr1 += __shfl_xor(lr1, 16, 64);
            lr1 += __shfl_xor(lr1, 32, 64);
            linv1 = 1.f / lr1;
        }
        // (c) P pack + quad-shuffle -> PV B-fragments (pad tiles = 0)
        uint pk0[8][2], pk1[8][2];
        #pragma unroll
        for (int ct = 0; ct < 8; ct++) {
            if (ct < NT8) {
                pk0[ct][0] = pack2bf(s0[ct][0], s0[ct][1]);
                pk0[ct][1] = pack2bf(s0[ct][2], s0[ct][3]);
                if (DUAL) {
                    pk1[ct][0] = pack2bf(s1[ct][0], s1[ct][1]);
                    pk1[ct][1] = pack2bf(s1[ct][2], s1[ct][3]);
                }
            } else {
                pk0[ct][0] = 0u; pk0[ct][1] = 0u;
                if (DUAL) { pk1[ct][0] = 0u; pk1[ct][1] = 0u; }
            }
        }
        short8 ap0[4], ap1[4];
        #pragma unroll
        for (int kt = 0; kt < 4; kt++) if (kt < NT4) {
            XPOSE(ap0[kt], pk0[2 * kt][0], pk0[2 * kt][1],
                           pk0[2 * kt + 1][0], pk0[2 * kt + 1][1]);
            if (DUAL)
                XPOSE(ap1[kt], pk1[2 * kt][0], pk1[2 * kt][1],
                               pk1[2 * kt + 1][0], pk1[2 * kt + 1][1]);
        }
        // (d) O^T = V^T P^T off shared vb
        uint opk0[4][2], opk1[4][2];
        #pragma unroll
        for (int ot = 0; ot < 4; ot++) {
            f32x4 o0 = {0.f, 0.f, 0.f, 0.f};
            f32x4 o1 = {0.f, 0.f, 0.f, 0.f};
            #pragma unroll
            for (int kt = 0; kt < 4; kt++) if (kt < NT4) {
                short8 vb = *(const short8*)(sm + vidx(ot * 16 + m16, kt * 32 + quad * 8));
                o0 = MFMA16(vb, ap0[kt], o0);
                if (DUAL) o1 = MFMA16(vb, ap1[kt], o1);
            }
            opk0[ot][0] = pack2bf(o0[0] * linv0, o0[1] * linv0);
            opk0[ot][1] = pack2bf(o0[2] * linv0, o0[3] * linv0);
            if (DUAL) {
                opk1[ot][0] = pack2bf(o1[0] * linv1, o1[1] * linv1);
                opk1[ot][1] = pack2bf(o1[2] * linv1, o1[3] * linv1);
            }
        }
        // (e) quad-shuffle O^T -> out-proj B-fragments
        short8 ao0[2], ao1[2];
        #pragma unroll
        for (int ks = 0; ks < 2; ks++) {
            XPOSE(ao0[ks], opk0[2 * ks][0], opk0[2 * ks][1],
                           opk0[2 * ks + 1][0], opk0[2 * ks + 1][1]);
            if (DUAL)
                XPOSE(ao1[ks], opk1[2 * ks][0], opk1[2 * ks][1],
                               opk1[2 * ks + 1][0], opk1[2 * ks + 1][1]);
        }
        // (f) out^T = WuT O^T off shared wb; 16B stores (+1 scalar at e=80)
        const int xrow0 = wave * 16 + m16;
        const int xrow1 = (wave + 4) * 16 + m16;
        float* orow0 = out + (off + xrow0) * C;
        float* orow1 = out + (off + xrow1) * C;
        #pragma unroll
        for (int ct = 0; ct < 6; ct++) {
            const ushort* wp = wuT + (ct * 16 + m16) * DK + quad * 8;
            const short8 wb0 = *(const short8*)(wp);
            const short8 wb1 = *(const short8*)(wp + 32);
            f32x4 A0 = {0.f, 0.f, 0.f, 0.f};
            f32x4 A1 = {0.f, 0.f, 0.f, 0.f};
            A0 = MFMA16(wb0, ao0[0], A0);
            A0 = MFMA16(wb1, ao0[1], A0);
            if (DUAL) {
                A1 = MFMA16(wb0, ao1[0], A1);
                A1 = MFMA16(wb1, ao1[1], A1);
            }
            const int e0 = ct * 16 + quad * 4;
            if (e0 + 3 < C) {
                const f32x4 b4 = *(const f32x4*)(bu + e0);
                A0[0] += b4[0]; A0[1] += b4[1]; A0[2] += b4[2]; A0[3] += b4[3];
                if (xrow0 < N) __builtin_memcpy(orow0 + e0, &A0, 16);
                if (DUAL) {
                    A1[0] += b4[0]; A1[1] += b4[1]; A1[2] += b4[2]; A1[3] += b4[3];
                    if (xrow1 < N) __builtin_memcpy(orow1 + e0, &A1, 16);
                }
            } else if (e0 == 80) {
                if (xrow0 < N) orow0[80] = A0[0] + bu[80];
                if (DUAL && xrow1 < N) orow1[80] = A1[0] + bu[80];
            }
        }
    };
    if (a0) {
        if (a1) phase2(BT{});
        else    phase2(BF{});
    }
}

// ---------------- launch ----------------
extern "C" void kernel_launch(void* const* d_in, const int* in_sizes, int n_in,
                              void* d_out, int out_size, void* d_ws, size_t ws_size,
                              hipStream_t stream) {
    const float* x      = (const float*)d_in[0];
    const int*   counts = (const int*)  d_in[1];
    const float* prior  = (const float*)d_in[2];
    const float* wq     = (const float*)d_in[3];
    const float* bq     = (const float*)d_in[4];
    const float* wk     = (const float*)d_in[5];
    const float* bk     = (const float*)d_in[6];
    const float* wv     = (const float*)d_in[7];
    const float* bv     = (const float*)d_in[8];
    const float* wu     = (const float*)d_in[9];
    const float* bu     = (const float*)d_in[10];
    float* out = (float*)d_out;

    const int B = in_sizes[1];   // 4096 groups

    // ws: meta[B] (offset | N<<24, LPT-sorted) | wqT | wkT | wvT | wuT
    uint*   meta = (uint*)d_ws;
    ushort* wqT = (ushort*)((char*)d_ws + (((size_t)B * sizeof(uint) + 255) & ~(size_t)255));
    ushort* wkT = wqT + DK * CP;
    ushort* wvT = wkT + DK * CP;
    ushort* wuT = wvT + DK * CP;

    prep_all<<<1 + (4 * DK * CP + 255) / 256, 256, 0, stream>>>(
        counts, meta, B, prior, wq, wk, wv, wu, wqT, wkT, wvT, wuT);
    ravnet_mfma<<<B, 256, 0, stream>>>(x, meta,
                                       wqT, wkT, wvT, wuT,
                                       bq, bk, bv, bu, out);
}